// Round 5
// baseline (874.712 us; speedup 1.0000x reference)
//
#include <hip/hip_runtime.h>
#include <hip/hip_bf16.h>

// Problem constants (static per reference)
#define NTOK 16384   // B*T
#define HD   512     // H
#define ED   8       // E experts
#define FD   2048    // F
#define CAP  5120    // capacity per expert
#define NA   32768   // NTOK * K(=2)

typedef __bf16 bf16x8 __attribute__((ext_vector_type(8)));
typedef float  f32x4  __attribute__((ext_vector_type(4)));

// Workspace layout (bytes). Total ~218 MB.
static constexpr size_t OFF_EIDX = 0;                                  // int[NA]
static constexpr size_t OFF_WGT  = 131072;                             // float[NA]
static constexpr size_t OFF_STOK = 262144;                             // int[ED*CAP]
static constexpr size_t OFF_SWGT = 458752;                             // float[ED*CAP]
static constexpr size_t OFF_W2T  = 1u << 20;                           // bf16[ED][HD][FD]
static constexpr size_t OFF_H    = OFF_W2T + (size_t)ED*HD*FD*2;       // bf16[ED][CAP][FD]
static constexpr size_t OFF_W1T  = OFF_H   + (size_t)ED*CAP*FD*2;      // bf16[ED][FD][HD]
static constexpr size_t OFF_XBF  = OFF_W1T + (size_t)ED*FD*HD*2;       // bf16[NTOK][HD]

__device__ __forceinline__ unsigned short f2bf(float f) {
    __bf16 b = (__bf16)f;
    return __builtin_bit_cast(unsigned short, b);
}

__device__ __forceinline__ void gl16(const unsigned short* src, unsigned short* lds_dst) {
    __builtin_amdgcn_global_load_lds(
        (const __attribute__((address_space(1))) void*)src,
        (__attribute__((address_space(3))) void*)lds_dst, 16, 0, 0);
}

// gelu(tanh approx) == v * sigmoid(2*0.79788456*(v + 0.044715 v^3))  (exact identity)
__device__ __forceinline__ float gelu_fast(float v) {
    const float u = 1.5957691216057308f * (v + 0.044715f * v * v * v);
    return v / (1.f + __expf(-u));
}

// ---------------------------------------------------------------------------
// Prep: fp32 -> bf16 cast (x), and cast+transpose (weights)
// ---------------------------------------------------------------------------
__global__ __launch_bounds__(256) void cast_x_kernel(
    const float4* __restrict__ x, ushort4* __restrict__ xb)
{
    const int i = blockIdx.x * 256 + threadIdx.x;
    float4 v = x[i];
    ushort4 o;
    o.x = f2bf(v.x); o.y = f2bf(v.y); o.z = f2bf(v.z); o.w = f2bf(v.w);
    xb[i] = o;
}

// in: [R][C] fp32 (per expert)  ->  out: [C][R] bf16 (per expert)
__global__ __launch_bounds__(256) void transpose_cast_kernel(
    const float* __restrict__ in, unsigned short* __restrict__ out, int R, int C)
{
    __shared__ unsigned short tile[32][33];
    const int e = blockIdx.z;
    in  += (size_t)e * R * C;
    out += (size_t)e * R * C;
    const int r0 = blockIdx.y * 32, c0 = blockIdx.x * 32;
    const int tr = threadIdx.x >> 3, tc = (threadIdx.x & 7) * 4;
    const float4 v = *(const float4*)(in + (size_t)(r0 + tr) * C + c0 + tc);
    tile[tr][tc + 0] = f2bf(v.x);
    tile[tr][tc + 1] = f2bf(v.y);
    tile[tr][tc + 2] = f2bf(v.z);
    tile[tr][tc + 3] = f2bf(v.w);
    __syncthreads();
    ushort4 o;
    o.x = tile[tc + 0][tr]; o.y = tile[tc + 1][tr];
    o.z = tile[tc + 2][tr]; o.w = tile[tc + 3][tr];
    *(ushort4*)(out + (size_t)(c0 + tr) * R + r0 + tc) = o;
}

// ---------------------------------------------------------------------------
// Router: logits = x @ router_w (exact fp32), top-2, softmax over the 2.
// ---------------------------------------------------------------------------
__global__ __launch_bounds__(256) void router_kernel(
    const float* __restrict__ x, const float* __restrict__ rw,
    int* __restrict__ eidx, float* __restrict__ wgt)
{
    __shared__ float rws[HD * ED];
    const int tid = threadIdx.x;
    for (int i = tid * 4; i < HD * ED; i += 256 * 4)
        *(float4*)(rws + i) = *(const float4*)(rw + i);
    __syncthreads();

    const int wid = tid >> 6, lane = tid & 63;
    const int t = blockIdx.x * 4 + wid;
    const float* xr = x + (size_t)t * HD;

    float acc[ED];
#pragma unroll
    for (int e = 0; e < ED; e++) acc[e] = 0.f;

    float4 xv0 = *(const float4*)(xr + lane * 8);
    float4 xv1 = *(const float4*)(xr + lane * 8 + 4);
    float xv[8] = {xv0.x, xv0.y, xv0.z, xv0.w, xv1.x, xv1.y, xv1.z, xv1.w};
#pragma unroll
    for (int j = 0; j < 8; j++) {
        const int h = lane * 8 + j;
#pragma unroll
        for (int e = 0; e < ED; e++) acc[e] += xv[j] * rws[h * ED + e];
    }
#pragma unroll
    for (int off = 32; off >= 1; off >>= 1) {
#pragma unroll
        for (int e = 0; e < ED; e++) acc[e] += __shfl_down(acc[e], off);
    }
    if (lane == 0) {
        int e0 = 0; float l0 = acc[0];
        for (int e = 1; e < ED; e++) if (acc[e] > l0) { l0 = acc[e]; e0 = e; }
        int e1 = 0; float l1 = -1e30f;
        for (int e = 0; e < ED; e++) {
            if (e == e0) continue;
            if (acc[e] > l1) { l1 = acc[e]; e1 = e; }
        }
        const float ex = expf(l1 - l0);
        const float inv = 1.f / (1.f + ex);
        eidx[t * 2 + 0] = e0;  eidx[t * 2 + 1] = e1;
        wgt [t * 2 + 0] = inv; wgt [t * 2 + 1] = ex * inv;
    }
}

// ---------------------------------------------------------------------------
// Deterministic slot assignment (stable-sort-by-expert semantics).
// ---------------------------------------------------------------------------
__global__ __launch_bounds__(1024) void scan_kernel(
    const int* __restrict__ eidx, const float* __restrict__ wgt,
    int* __restrict__ stok, float* __restrict__ swgt)
{
    __shared__ int running[ED];
    __shared__ int wcnt[16][ED];
    const int tid = threadIdx.x;

    for (int i = tid; i < ED * CAP; i += 1024) stok[i] = -1;
    if (tid < ED) running[tid] = 0;
    __syncthreads();

    const int lane = tid & 63, wid = tid >> 6;
    const unsigned long long below = (1ull << lane) - 1ull;

    for (int c = 0; c < NA / 1024; c++) {
        const int a = c * 1024 + tid;
        const int e = eidx[a];
        const float w = wgt[a];
        int myrank = 0;
#pragma unroll
        for (int ee = 0; ee < ED; ee++) {
            unsigned long long m = __ballot(e == ee);
            if (ee == e) myrank = __popcll(m & below);
            if (lane == 0) wcnt[wid][ee] = __popcll(m);
        }
        __syncthreads();
        int woff = 0;
        for (int ww = 0; ww < wid; ww++) woff += wcnt[ww][e];
        const int slot = running[e] + woff + myrank;
        if (slot < CAP) {
            stok[e * CAP + slot] = a >> 1;   // token = a / K
            swgt[e * CAP + slot] = w;
        }
        __syncthreads();
        if (tid < ED) {
            int tot = 0;
            for (int ww = 0; ww < 16; ww++) tot += wcnt[ww][tid];
            running[tid] += tot;
        }
        __syncthreads();
    }
}

// ---------------------------------------------------------------------------
// MFMA GEMM: 128x128 tile, BK=64, LDS double-buffered via async
// global_load_lds. One __syncthreads per BK=64 phase; each phase does 32
// MFMAs/wave (2x the work per barrier-drain of the BK=32 version — the drain
// is floored at memory latency, so work-per-drain is what matters).
// Grid 1-D: blockIdx.x & 7 == expert -> expert pinned to one XCD so its 2 MB
// weight slab stays L2-resident; m-tile fastest within an expert.
// FUSE=false: hout = gelu(A@B + bias) [bf16]. FUSE=true: atomic combine.
// ---------------------------------------------------------------------------
template<int KD, int ND, int MT, bool FUSE>
__global__ __launch_bounds__(256) void gemm_mfma(
    const unsigned short* __restrict__ Abase,
    const unsigned short* __restrict__ Bt,
    const float* __restrict__ bias,
    const int* __restrict__ stok,
    const float* __restrict__ swgt,
    unsigned short* __restrict__ hout,
    float* __restrict__ out)
{
    // [buf][kchunk(8)][row(128)][8 bf16] : 16 KB per buf per matrix, 64 KB total
    __shared__ __align__(16) unsigned short As[2 * 8192];
    __shared__ __align__(16) unsigned short Bs[2 * 8192];

    const int tid = threadIdx.x;
    const int e  = blockIdx.x & 7;          // expert -> XCD (round-robin dispatch)
    const int t  = blockIdx.x >> 3;
    const int n0 = (t / MT) * 128;          // m fastest: same-expert stream reuses B n-slab
    const int m0 = (t % MT) * 128;

    // Staging: thread owns row r, 16B k-chunks c0, c0+2, c0+4, c0+6
    const int r  = tid & 127;
    const int c0 = tid >> 7;

    size_t arow_idx;
    if (!FUSE) {
        const int tok = stok[e * CAP + m0 + r];
        arow_idx = (size_t)(tok >= 0 ? tok : 0);   // dropped -> row 0 (weight 0 kills it)
    } else {
        arow_idx = (size_t)(e * CAP + m0 + r);
    }
    const unsigned short* arow = Abase + arow_idx * KD;
    const unsigned short* brow = Bt + ((size_t)e * ND + n0 + r) * KD;

    const int lane = tid & 63;
    const int wid  = tid >> 6;
    const int wrow = (wid & 1) * 64;
    const int wcol = (wid >> 1) * 64;
    const int l15  = lane & 15;
    const int quad = lane >> 4;

    f32x4 acc[4][4];
#pragma unroll
    for (int i = 0; i < 4; i++)
#pragma unroll
        for (int j = 0; j < 4; j++) acc[i][j] = (f32x4)0.f;

    // DMA one BK=64 tile (A+B) into buf: 8 insts/thread, 32 KB/block
#define STAGE(BUF, KOFF)                                                       \
    {                                                                          \
        const unsigned short* a2 = arow + (KOFF);                              \
        const unsigned short* b2 = brow + (KOFF);                              \
        _Pragma("unroll")                                                      \
        for (int cc = 0; cc < 4; cc++) {                                       \
            const int ch = c0 + cc * 2;                                        \
            gl16(a2 + ch * 8, &As[(BUF) * 8192 + (ch * 128 + r) * 8]);         \
            gl16(b2 + ch * 8, &Bs[(BUF) * 8192 + (ch * 128 + r) * 8]);         \
        }                                                                      \
    }

    // 32 MFMAs on buf (two K=32 sub-steps)
#define COMPUTE(BUF)                                                           \
    {                                                                          \
        const bf16x8* Av = (const bf16x8*)(As + (BUF) * 8192);                 \
        const bf16x8* Bv = (const bf16x8*)(Bs + (BUF) * 8192);                 \
        _Pragma("unroll")                                                      \
        for (int kk = 0; kk < 2; kk++) {                                       \
            const int co = (kk * 4 + quad) * 128;                              \
            bf16x8 af[4], bfv[4];                                              \
            _Pragma("unroll")                                                  \
            for (int i = 0; i < 4; i++) af[i]  = Av[co + wrow + i * 16 + l15]; \
            _Pragma("unroll")                                                  \
            for (int j = 0; j < 4; j++) bfv[j] = Bv[co + wcol + j * 16 + l15]; \
            _Pragma("unroll")                                                  \
            for (int i = 0; i < 4; i++)                                        \
                _Pragma("unroll")                                              \
                for (int j = 0; j < 4; j++)                                    \
                    acc[i][j] = __builtin_amdgcn_mfma_f32_16x16x32_bf16(       \
                        af[i], bfv[j], acc[i][j], 0, 0, 0);                    \
        }                                                                      \
    }

    // Prologue: tile 0 -> buf0
    STAGE(0, 0)
    __syncthreads();

    for (int kc = 0; kc < KD; kc += 128) {
        // phase A: prefetch tile kc+64 -> buf1, compute buf0 (tile kc)
        STAGE(1, kc + 64)
        COMPUTE(0)
        __syncthreads();
        // phase B: prefetch tile kc+128 -> buf0, compute buf1 (tile kc+64)
        if (kc + 128 < KD) STAGE(0, kc + 128)
        COMPUTE(1)
        __syncthreads();
    }
#undef STAGE
#undef COMPUTE

    // Epilogue. C/D layout: col = lane&15, row = quad*4 + reg.
    if (!FUSE) {
#pragma unroll
        for (int i = 0; i < 4; i++) {
#pragma unroll
            for (int g = 0; g < 4; g++) {
                const int m = wrow + i * 16 + quad * 4 + g;
                unsigned short* hrow = hout + ((size_t)e * CAP + m0 + m) * FD + n0;
#pragma unroll
                for (int j = 0; j < 4; j++) {
                    const int n = wcol + j * 16 + l15;
                    const float v = acc[i][j][g] + bias[(size_t)e * ND + n0 + n];
                    hrow[n] = f2bf(gelu_fast(v));
                }
            }
        }
    } else {
#pragma unroll
        for (int i = 0; i < 4; i++) {
#pragma unroll
            for (int g = 0; g < 4; g++) {
                const int m = wrow + i * 16 + quad * 4 + g;
                const int tok = stok[e * CAP + m0 + m];
                if (tok >= 0) {
                    const float w = swgt[e * CAP + m0 + m];
                    float* orow = out + (size_t)tok * HD + n0;
#pragma unroll
                    for (int j = 0; j < 4; j++) {
                        const int n = wcol + j * 16 + l15;
                        const float v = (acc[i][j][g] + bias[(size_t)e * ND + n0 + n]) * w;
                        atomicAdd(orow + n, v);
                    }
                }
            }
        }
    }
}

extern "C" void kernel_launch(void* const* d_in, const int* in_sizes, int n_in,
                              void* d_out, int out_size, void* d_ws, size_t ws_size,
                              hipStream_t stream)
{
    const float* x  = (const float*)d_in[0];
    const float* rw = (const float*)d_in[1];
    const float* w1 = (const float*)d_in[2];
    const float* b1 = (const float*)d_in[3];
    const float* w2 = (const float*)d_in[4];
    const float* b2 = (const float*)d_in[5];
    float* out = (float*)d_out;

    char* ws = (char*)d_ws;
    int*   eidx = (int*)  (ws + OFF_EIDX);
    float* wgt  = (float*)(ws + OFF_WGT);
    int*   stok = (int*)  (ws + OFF_STOK);
    float* swgt = (float*)(ws + OFF_SWGT);
    unsigned short* w2t  = (unsigned short*)(ws + OFF_W2T);
    unsigned short* hbuf = (unsigned short*)(ws + OFF_H);
    unsigned short* w1t  = (unsigned short*)(ws + OFF_W1T);
    unsigned short* xbf  = (unsigned short*)(ws + OFF_XBF);

    cast_x_kernel<<<NTOK * HD / 1024, 256, 0, stream>>>((const float4*)x, (ushort4*)xbf);
    transpose_cast_kernel<<<dim3(FD / 32, HD / 32, ED), 256, 0, stream>>>(w1, w1t, HD, FD);
    transpose_cast_kernel<<<dim3(HD / 32, FD / 32, ED), 256, 0, stream>>>(w2, w2t, FD, HD);
    router_kernel<<<NTOK / 4, 256, 0, stream>>>(x, rw, eidx, wgt);
    scan_kernel<<<1, 1024, 0, stream>>>(eidx, wgt, stok, swgt);
    hipMemsetAsync(d_out, 0, (size_t)out_size * sizeof(float), stream);

    // GEMM1: h = gelu(gather(x) @ w1 + b1)  [bf16]
    gemm_mfma<HD, FD, CAP/128, false>
        <<<(CAP/128) * (FD/128) * ED, 256, 0, stream>>>(
        xbf, w1t, b1, stok, nullptr, hbuf, nullptr);

    // GEMM2 + fused combine: out[tok] += (h @ w2 + b2) * weight
    gemm_mfma<FD, HD, CAP/128, true>
        <<<(CAP/128) * (HD/128) * ED, 256, 0, stream>>>(
        hbuf, w2t, b2, stok, swgt, nullptr, out);
}

// Round 6
// 683.215 us; speedup vs baseline: 1.2803x; 1.2803x over previous
//
#include <hip/hip_runtime.h>
#include <hip/hip_bf16.h>

// Problem constants (static per reference)
#define NTOK 16384   // B*T
#define HD   512     // H
#define ED   8       // E experts
#define FD   2048    // F
#define CAP  5120    // capacity per expert
#define NA   32768   // NTOK * K(=2)

typedef __bf16 bf16x8 __attribute__((ext_vector_type(8)));
typedef float  f32x4  __attribute__((ext_vector_type(4)));

// Workspace layout (bytes). Total ~218 MB.
static constexpr size_t OFF_EIDX = 0;                                  // int[NA]
static constexpr size_t OFF_WGT  = 131072;                             // float[NA]
static constexpr size_t OFF_STOK = 262144;                             // int[ED*CAP]
static constexpr size_t OFF_SWGT = 458752;                             // float[ED*CAP]
static constexpr size_t OFF_W2T  = 1u << 20;                           // bf16[ED][HD][FD]
static constexpr size_t OFF_H    = OFF_W2T + (size_t)ED*HD*FD*2;       // bf16[ED][CAP][FD]
static constexpr size_t OFF_W1T  = OFF_H   + (size_t)ED*CAP*FD*2;      // bf16[ED][FD][HD]
static constexpr size_t OFF_XBF  = OFF_W1T + (size_t)ED*FD*HD*2;       // bf16[NTOK][HD]

__device__ __forceinline__ unsigned short f2bf(float f) {
    __bf16 b = (__bf16)f;
    return __builtin_bit_cast(unsigned short, b);
}

__device__ __forceinline__ void gl16(const unsigned short* src, unsigned short* lds_dst) {
    __builtin_amdgcn_global_load_lds(
        (const __attribute__((address_space(1))) void*)src,
        (__attribute__((address_space(3))) void*)lds_dst, 16, 0, 0);
}

// gelu(tanh approx) == v * sigmoid(2*0.79788456*(v + 0.044715 v^3))  (exact identity)
__device__ __forceinline__ float gelu_fast(float v) {
    const float u = 1.5957691216057308f * (v + 0.044715f * v * v * v);
    return v / (1.f + __expf(-u));
}

// ---------------------------------------------------------------------------
// Prep: fp32 -> bf16 cast (x), and cast+transpose (weights)
// ---------------------------------------------------------------------------
__global__ __launch_bounds__(256) void cast_x_kernel(
    const float4* __restrict__ x, ushort4* __restrict__ xb)
{
    const int i = blockIdx.x * 256 + threadIdx.x;
    float4 v = x[i];
    ushort4 o;
    o.x = f2bf(v.x); o.y = f2bf(v.y); o.z = f2bf(v.z); o.w = f2bf(v.w);
    xb[i] = o;
}

// in: [R][C] fp32 (per expert)  ->  out: [C][R] bf16 (per expert)
__global__ __launch_bounds__(256) void transpose_cast_kernel(
    const float* __restrict__ in, unsigned short* __restrict__ out, int R, int C)
{
    __shared__ unsigned short tile[32][33];
    const int e = blockIdx.z;
    in  += (size_t)e * R * C;
    out += (size_t)e * R * C;
    const int r0 = blockIdx.y * 32, c0 = blockIdx.x * 32;
    const int tr = threadIdx.x >> 3, tc = (threadIdx.x & 7) * 4;
    const float4 v = *(const float4*)(in + (size_t)(r0 + tr) * C + c0 + tc);
    tile[tr][tc + 0] = f2bf(v.x);
    tile[tr][tc + 1] = f2bf(v.y);
    tile[tr][tc + 2] = f2bf(v.z);
    tile[tr][tc + 3] = f2bf(v.w);
    __syncthreads();
    ushort4 o;
    o.x = tile[tc + 0][tr]; o.y = tile[tc + 1][tr];
    o.z = tile[tc + 2][tr]; o.w = tile[tc + 3][tr];
    *(ushort4*)(out + (size_t)(c0 + tr) * R + r0 + tc) = o;
}

// ---------------------------------------------------------------------------
// Router: logits = x @ router_w (exact fp32), top-2, softmax over the 2.
// ---------------------------------------------------------------------------
__global__ __launch_bounds__(256) void router_kernel(
    const float* __restrict__ x, const float* __restrict__ rw,
    int* __restrict__ eidx, float* __restrict__ wgt)
{
    __shared__ float rws[HD * ED];
    const int tid = threadIdx.x;
    for (int i = tid * 4; i < HD * ED; i += 256 * 4)
        *(float4*)(rws + i) = *(const float4*)(rw + i);
    __syncthreads();

    const int wid = tid >> 6, lane = tid & 63;
    const int t = blockIdx.x * 4 + wid;
    const float* xr = x + (size_t)t * HD;

    float acc[ED];
#pragma unroll
    for (int e = 0; e < ED; e++) acc[e] = 0.f;

    float4 xv0 = *(const float4*)(xr + lane * 8);
    float4 xv1 = *(const float4*)(xr + lane * 8 + 4);
    float xv[8] = {xv0.x, xv0.y, xv0.z, xv0.w, xv1.x, xv1.y, xv1.z, xv1.w};
#pragma unroll
    for (int j = 0; j < 8; j++) {
        const int h = lane * 8 + j;
#pragma unroll
        for (int e = 0; e < ED; e++) acc[e] += xv[j] * rws[h * ED + e];
    }
#pragma unroll
    for (int off = 32; off >= 1; off >>= 1) {
#pragma unroll
        for (int e = 0; e < ED; e++) acc[e] += __shfl_down(acc[e], off);
    }
    if (lane == 0) {
        int e0 = 0; float l0 = acc[0];
        for (int e = 1; e < ED; e++) if (acc[e] > l0) { l0 = acc[e]; e0 = e; }
        int e1 = 0; float l1 = -1e30f;
        for (int e = 0; e < ED; e++) {
            if (e == e0) continue;
            if (acc[e] > l1) { l1 = acc[e]; e1 = e; }
        }
        const float ex = expf(l1 - l0);
        const float inv = 1.f / (1.f + ex);
        eidx[t * 2 + 0] = e0;  eidx[t * 2 + 1] = e1;
        wgt [t * 2 + 0] = inv; wgt [t * 2 + 1] = ex * inv;
    }
}

// ---------------------------------------------------------------------------
// Deterministic slot assignment (stable-sort-by-expert semantics).
// ---------------------------------------------------------------------------
__global__ __launch_bounds__(1024) void scan_kernel(
    const int* __restrict__ eidx, const float* __restrict__ wgt,
    int* __restrict__ stok, float* __restrict__ swgt)
{
    __shared__ int running[ED];
    __shared__ int wcnt[16][ED];
    const int tid = threadIdx.x;

    for (int i = tid; i < ED * CAP; i += 1024) stok[i] = -1;
    if (tid < ED) running[tid] = 0;
    __syncthreads();

    const int lane = tid & 63, wid = tid >> 6;
    const unsigned long long below = (1ull << lane) - 1ull;

    for (int c = 0; c < NA / 1024; c++) {
        const int a = c * 1024 + tid;
        const int e = eidx[a];
        const float w = wgt[a];
        int myrank = 0;
#pragma unroll
        for (int ee = 0; ee < ED; ee++) {
            unsigned long long m = __ballot(e == ee);
            if (ee == e) myrank = __popcll(m & below);
            if (lane == 0) wcnt[wid][ee] = __popcll(m);
        }
        __syncthreads();
        int woff = 0;
        for (int ww = 0; ww < wid; ww++) woff += wcnt[ww][e];
        const int slot = running[e] + woff + myrank;
        if (slot < CAP) {
            stok[e * CAP + slot] = a >> 1;   // token = a / K
            swgt[e * CAP + slot] = w;
        }
        __syncthreads();
        if (tid < ED) {
            int tot = 0;
            for (int ww = 0; ww < 16; ww++) tot += wcnt[ww][tid];
            running[tid] += tot;
        }
        __syncthreads();
    }
}

// ---------------------------------------------------------------------------
// MFMA GEMM: 128x128 tile, BK=32, LDS double-buffered via async
// global_load_lds (R4 structure — 32 KB LDS, occ ~27%).
// Work mapping (the R6 change): 1-D grid, id%8 == expert == XCD (round-robin
// dispatch heuristic), and n is the FASTEST axis within an (e, m) group, so
// the 16 (GEMM1) / 4 (GEMM2) n-tiles sharing one m-tile's gathered A rows run
// back-to-back on one XCD: A fetched into L2 once, reused by every n-tile.
// Per-XCD L2 working set: A group 128 KB + whole expert weight slab 2 MB.
// FUSE=false: hout = gelu(A@B + bias) [bf16]. FUSE=true: atomic combine.
// ---------------------------------------------------------------------------
template<int KD, int ND, int NT, bool FUSE>
__global__ __launch_bounds__(256) void gemm_mfma(
    const unsigned short* __restrict__ Abase,
    const unsigned short* __restrict__ Bt,
    const float* __restrict__ bias,
    const int* __restrict__ stok,
    const float* __restrict__ swgt,
    unsigned short* __restrict__ hout,
    float* __restrict__ out)
{
    // [buf][kchunk(4)][row(128)][8 bf16] : 8 KB per buf per matrix, 32 KB total
    __shared__ __align__(16) unsigned short As[2 * 4096];
    __shared__ __align__(16) unsigned short Bs[2 * 4096];

    const int tid = threadIdx.x;
    const int e  = blockIdx.x & 7;          // expert == XCD (id%8 round-robin)
    const int g  = blockIdx.x >> 3;
    const int n0 = (g % NT) * 128;          // n fastest: reuse gathered A rows in L2
    const int m0 = (g / NT) * 128;

    // Staging: thread owns row r, 16B-chunks c0 and c0+2
    const int r  = tid & 127;
    const int c0 = tid >> 7;

    size_t arow_idx;
    if (!FUSE) {
        const int tok = stok[e * CAP + m0 + r];
        arow_idx = (size_t)(tok >= 0 ? tok : 0);   // dropped -> row 0 (weight 0 kills it)
    } else {
        arow_idx = (size_t)(e * CAP + m0 + r);
    }
    const unsigned short* arow = Abase + arow_idx * KD;
    const unsigned short* brow = Bt + ((size_t)e * ND + n0 + r) * KD;

    unsigned short* AsD0 = &As[(c0 * 128 + r) * 8];
    unsigned short* AsD1 = &As[((c0 + 2) * 128 + r) * 8];
    unsigned short* BsD0 = &Bs[(c0 * 128 + r) * 8];
    unsigned short* BsD1 = &Bs[((c0 + 2) * 128 + r) * 8];

    const int lane = tid & 63;
    const int wid  = tid >> 6;
    const int wrow = (wid & 1) * 64;
    const int wcol = (wid >> 1) * 64;
    const int l15  = lane & 15;
    const int quad = lane >> 4;
    const int foff = quad * 128 + l15;

    f32x4 acc[4][4];
#pragma unroll
    for (int i = 0; i < 4; i++)
#pragma unroll
        for (int j = 0; j < 4; j++) acc[i][j] = (f32x4)0.f;

    // Prologue: DMA tile 0 into buf 0
    gl16(arow + c0 * 8,       AsD0);
    gl16(arow + (c0 + 2) * 8, AsD1);
    gl16(brow + c0 * 8,       BsD0);
    gl16(brow + (c0 + 2) * 8, BsD1);
    __syncthreads();

#define COMPUTE(PBUF)                                                          \
    {                                                                          \
        const bf16x8* Av = (const bf16x8*)(As + (PBUF) * 4096);                \
        const bf16x8* Bv = (const bf16x8*)(Bs + (PBUF) * 4096);                \
        bf16x8 af[4], bfv[4];                                                  \
        _Pragma("unroll")                                                      \
        for (int i = 0; i < 4; i++) af[i]  = Av[foff + wrow + i * 16];         \
        _Pragma("unroll")                                                      \
        for (int j = 0; j < 4; j++) bfv[j] = Bv[foff + wcol + j * 16];         \
        _Pragma("unroll")                                                      \
        for (int i = 0; i < 4; i++)                                            \
            _Pragma("unroll")                                                  \
            for (int j = 0; j < 4; j++)                                        \
                acc[i][j] = __builtin_amdgcn_mfma_f32_16x16x32_bf16(           \
                    af[i], bfv[j], acc[i][j], 0, 0, 0);                        \
    }

    for (int kc = 0; kc < KD; kc += 64) {
        // phase 0: prefetch tile (kc+32) -> buf1, compute on buf0 (tile kc)
        if (kc + 32 < KD) {
            const unsigned short* a2 = arow + kc + 32;
            const unsigned short* b2 = brow + kc + 32;
            gl16(a2 + c0 * 8,       AsD0 + 4096);
            gl16(a2 + (c0 + 2) * 8, AsD1 + 4096);
            gl16(b2 + c0 * 8,       BsD0 + 4096);
            gl16(b2 + (c0 + 2) * 8, BsD1 + 4096);
        }
        COMPUTE(0);
        __syncthreads();

        // phase 1: prefetch tile (kc+64) -> buf0, compute on buf1 (tile kc+32)
        if (kc + 64 < KD) {
            const unsigned short* a2 = arow + kc + 64;
            const unsigned short* b2 = brow + kc + 64;
            gl16(a2 + c0 * 8,       AsD0);
            gl16(a2 + (c0 + 2) * 8, AsD1);
            gl16(b2 + c0 * 8,       BsD0);
            gl16(b2 + (c0 + 2) * 8, BsD1);
        }
        COMPUTE(1);
        __syncthreads();
    }
#undef COMPUTE

    // Epilogue. C/D layout: col = lane&15, row = quad*4 + reg.
    if (!FUSE) {
#pragma unroll
        for (int i = 0; i < 4; i++) {
#pragma unroll
            for (int g2 = 0; g2 < 4; g2++) {
                const int m = wrow + i * 16 + quad * 4 + g2;
                unsigned short* hrow = hout + ((size_t)e * CAP + m0 + m) * FD + n0;
#pragma unroll
                for (int j = 0; j < 4; j++) {
                    const int n = wcol + j * 16 + l15;
                    const float v = acc[i][j][g2] + bias[(size_t)e * ND + n0 + n];
                    hrow[n] = f2bf(gelu_fast(v));
                }
            }
        }
    } else {
#pragma unroll
        for (int i = 0; i < 4; i++) {
#pragma unroll
            for (int g2 = 0; g2 < 4; g2++) {
                const int m = wrow + i * 16 + quad * 4 + g2;
                const int tok = stok[e * CAP + m0 + m];
                if (tok >= 0) {
                    const float w = swgt[e * CAP + m0 + m];
                    float* orow = out + (size_t)tok * HD + n0;
#pragma unroll
                    for (int j = 0; j < 4; j++) {
                        const int n = wcol + j * 16 + l15;
                        const float v = (acc[i][j][g2] + bias[(size_t)e * ND + n0 + n]) * w;
                        atomicAdd(orow + n, v);
                    }
                }
            }
        }
    }
}

extern "C" void kernel_launch(void* const* d_in, const int* in_sizes, int n_in,
                              void* d_out, int out_size, void* d_ws, size_t ws_size,
                              hipStream_t stream)
{
    const float* x  = (const float*)d_in[0];
    const float* rw = (const float*)d_in[1];
    const float* w1 = (const float*)d_in[2];
    const float* b1 = (const float*)d_in[3];
    const float* w2 = (const float*)d_in[4];
    const float* b2 = (const float*)d_in[5];
    float* out = (float*)d_out;

    char* ws = (char*)d_ws;
    int*   eidx = (int*)  (ws + OFF_EIDX);
    float* wgt  = (float*)(ws + OFF_WGT);
    int*   stok = (int*)  (ws + OFF_STOK);
    float* swgt = (float*)(ws + OFF_SWGT);
    unsigned short* w2t  = (unsigned short*)(ws + OFF_W2T);
    unsigned short* hbuf = (unsigned short*)(ws + OFF_H);
    unsigned short* w1t  = (unsigned short*)(ws + OFF_W1T);
    unsigned short* xbf  = (unsigned short*)(ws + OFF_XBF);

    cast_x_kernel<<<NTOK * HD / 1024, 256, 0, stream>>>((const float4*)x, (ushort4*)xbf);
    transpose_cast_kernel<<<dim3(FD / 32, HD / 32, ED), 256, 0, stream>>>(w1, w1t, HD, FD);
    transpose_cast_kernel<<<dim3(HD / 32, FD / 32, ED), 256, 0, stream>>>(w2, w2t, FD, HD);
    router_kernel<<<NTOK / 4, 256, 0, stream>>>(x, rw, eidx, wgt);
    scan_kernel<<<1, 1024, 0, stream>>>(eidx, wgt, stok, swgt);
    hipMemsetAsync(d_out, 0, (size_t)out_size * sizeof(float), stream);

    // GEMM1: h = gelu(gather(x) @ w1 + b1)  [bf16]
    gemm_mfma<HD, FD, FD/128, false>
        <<<8 * (FD/128) * (CAP/128), 256, 0, stream>>>(
        xbf, w1t, b1, stok, nullptr, hbuf, nullptr);

    // GEMM2 + fused combine: out[tok] += (h @ w2 + b2) * weight
    gemm_mfma<FD, HD, HD/128, true>
        <<<8 * (HD/128) * (CAP/128), 256, 0, stream>>>(
        hbuf, w2t, b2, stok, swgt, nullptr, out);
}

// Round 7
// 628.970 us; speedup vs baseline: 1.3907x; 1.0862x over previous
//
#include <hip/hip_runtime.h>
#include <hip/hip_bf16.h>

// Problem constants (static per reference)
#define NTOK 16384   // B*T
#define HD   512     // H
#define ED   8       // E experts
#define FD   2048    // F
#define CAP  5120    // capacity per expert
#define NA   32768   // NTOK * K(=2)

typedef __bf16 bf16x8 __attribute__((ext_vector_type(8)));
typedef float  f32x4  __attribute__((ext_vector_type(4)));

// Workspace layout (bytes). Total ~218 MB.
static constexpr size_t OFF_EIDX = 0;                                  // int[NA]
static constexpr size_t OFF_WGT  = 131072;                             // float[NA]
static constexpr size_t OFF_STOK = 262144;                             // int[ED*CAP]
static constexpr size_t OFF_SWGT = 458752;                             // float[ED*CAP]
static constexpr size_t OFF_W2T  = 1u << 20;                           // bf16[ED][HD][FD]
static constexpr size_t OFF_H    = OFF_W2T + (size_t)ED*HD*FD*2;       // bf16[ED][CAP][FD]
static constexpr size_t OFF_W1T  = OFF_H   + (size_t)ED*CAP*FD*2;      // bf16[ED][FD][HD]
static constexpr size_t OFF_XBF  = OFF_W1T + (size_t)ED*FD*HD*2;       // bf16[NTOK][HD]

__device__ __forceinline__ unsigned short f2bf(float f) {
    __bf16 b = (__bf16)f;
    return __builtin_bit_cast(unsigned short, b);
}

// gelu(tanh approx) == v * sigmoid(2*0.79788456*(v + 0.044715 v^3))  (exact identity)
__device__ __forceinline__ float gelu_fast(float v) {
    const float u = 1.5957691216057308f * (v + 0.044715f * v * v * v);
    return v / (1.f + __expf(-u));
}

// ---------------------------------------------------------------------------
// in: [R][C] fp32 (per expert)  ->  out: [C][R] bf16 (per expert)
// ---------------------------------------------------------------------------
__global__ __launch_bounds__(256) void transpose_cast_kernel(
    const float* __restrict__ in, unsigned short* __restrict__ out, int R, int C)
{
    __shared__ unsigned short tile[32][33];
    const int e = blockIdx.z;
    in  += (size_t)e * R * C;
    out += (size_t)e * R * C;
    const int r0 = blockIdx.y * 32, c0 = blockIdx.x * 32;
    const int tr = threadIdx.x >> 3, tc = (threadIdx.x & 7) * 4;
    const float4 v = *(const float4*)(in + (size_t)(r0 + tr) * C + c0 + tc);
    tile[tr][tc + 0] = f2bf(v.x);
    tile[tr][tc + 1] = f2bf(v.y);
    tile[tr][tc + 2] = f2bf(v.z);
    tile[tr][tc + 3] = f2bf(v.w);
    __syncthreads();
    ushort4 o;
    o.x = tile[tc + 0][tr]; o.y = tile[tc + 1][tr];
    o.z = tile[tc + 2][tr]; o.w = tile[tc + 3][tr];
    *(ushort4*)(out + (size_t)(c0 + tr) * R + r0 + tc) = o;
}

// ---------------------------------------------------------------------------
// Router (+ fused x->bf16 cast): logits = x @ router_w (fp32), top-2, softmax.
// Each wave reads its token's full row; lanes also emit the bf16 copy.
// ---------------------------------------------------------------------------
__global__ __launch_bounds__(256) void router_kernel(
    const float* __restrict__ x, const float* __restrict__ rw,
    int* __restrict__ eidx, float* __restrict__ wgt,
    unsigned short* __restrict__ xbf)
{
    __shared__ float rws[HD * ED];
    const int tid = threadIdx.x;
    for (int i = tid * 4; i < HD * ED; i += 256 * 4)
        *(float4*)(rws + i) = *(const float4*)(rw + i);
    __syncthreads();

    const int wid = tid >> 6, lane = tid & 63;
    const int t = blockIdx.x * 4 + wid;
    const float* xr = x + (size_t)t * HD;

    float acc[ED];
#pragma unroll
    for (int e = 0; e < ED; e++) acc[e] = 0.f;

    float4 xv0 = *(const float4*)(xr + lane * 8);
    float4 xv1 = *(const float4*)(xr + lane * 8 + 4);
    float xv[8] = {xv0.x, xv0.y, xv0.z, xv0.w, xv1.x, xv1.y, xv1.z, xv1.w};

    // fused bf16 cast of x (saves a separate 50 MB pass)
    union { unsigned short us[8]; uint4 v; } pk;
#pragma unroll
    for (int j = 0; j < 8; j++) pk.us[j] = f2bf(xv[j]);
    *(uint4*)(xbf + (size_t)t * HD + lane * 8) = pk.v;

#pragma unroll
    for (int j = 0; j < 8; j++) {
        const int h = lane * 8 + j;
#pragma unroll
        for (int e = 0; e < ED; e++) acc[e] += xv[j] * rws[h * ED + e];
    }
#pragma unroll
    for (int off = 32; off >= 1; off >>= 1) {
#pragma unroll
        for (int e = 0; e < ED; e++) acc[e] += __shfl_down(acc[e], off);
    }
    if (lane == 0) {
        int e0 = 0; float l0 = acc[0];
        for (int e = 1; e < ED; e++) if (acc[e] > l0) { l0 = acc[e]; e0 = e; }
        int e1 = 0; float l1 = -1e30f;
        for (int e = 0; e < ED; e++) {
            if (e == e0) continue;
            if (acc[e] > l1) { l1 = acc[e]; e1 = e; }
        }
        const float ex = expf(l1 - l0);
        const float inv = 1.f / (1.f + ex);
        eidx[t * 2 + 0] = e0;  eidx[t * 2 + 1] = e1;
        wgt [t * 2 + 0] = inv; wgt [t * 2 + 1] = ex * inv;
    }
}

// ---------------------------------------------------------------------------
// Deterministic slot assignment (stable-sort-by-expert semantics).
// ---------------------------------------------------------------------------
__global__ __launch_bounds__(1024) void scan_kernel(
    const int* __restrict__ eidx, const float* __restrict__ wgt,
    int* __restrict__ stok, float* __restrict__ swgt)
{
    __shared__ int running[ED];
    __shared__ int wcnt[16][ED];
    const int tid = threadIdx.x;

    for (int i = tid; i < ED * CAP; i += 1024) stok[i] = -1;
    if (tid < ED) running[tid] = 0;
    __syncthreads();

    const int lane = tid & 63, wid = tid >> 6;
    const unsigned long long below = (1ull << lane) - 1ull;

    for (int c = 0; c < NA / 1024; c++) {
        const int a = c * 1024 + tid;
        const int e = eidx[a];
        const float w = wgt[a];
        int myrank = 0;
#pragma unroll
        for (int ee = 0; ee < ED; ee++) {
            unsigned long long m = __ballot(e == ee);
            if (ee == e) myrank = __popcll(m & below);
            if (lane == 0) wcnt[wid][ee] = __popcll(m);
        }
        __syncthreads();
        int woff = 0;
        for (int ww = 0; ww < wid; ww++) woff += wcnt[ww][e];
        const int slot = running[e] + woff + myrank;
        if (slot < CAP) {
            stok[e * CAP + slot] = a >> 1;   // token = a / K
            swgt[e * CAP + slot] = w;
        }
        __syncthreads();
        if (tid < ED) {
            int tot = 0;
            for (int ww = 0; ww < 16; ww++) tot += wcnt[ww][tid];
            running[tid] += tot;
        }
        __syncthreads();
    }
}

// ---------------------------------------------------------------------------
// MFMA GEMM, VGPR-staged software pipeline: 128x128 tile, BK=32, 4 waves.
// Key change vs R6: staging goes global->VGPR->ds_write (NOT global_load_lds),
// so __syncthreads no longer drains vmcnt. ONE barrier per K-step; the vmcnt
// wait (at the ds_write) is for loads issued a full iteration earlier — the
// load latency is hidden behind an entire compute phase across all waves.
// Work mapping (kept from R6): id%8 == expert == XCD, n fastest within (e,m)
// group -> gathered A rows fetched into L2 once, reused by all n-tiles;
// expert weight slab (2 MB) stays L2-resident.
// FUSE=false: hout = gelu(A@B + bias) [bf16]. FUSE=true: atomic combine.
// ---------------------------------------------------------------------------
template<int KD, int ND, int NT, bool FUSE>
__global__ __launch_bounds__(256) void gemm_mfma(
    const unsigned short* __restrict__ Abase,
    const unsigned short* __restrict__ Bt,
    const float* __restrict__ bias,
    const int* __restrict__ stok,
    const float* __restrict__ swgt,
    unsigned short* __restrict__ hout,
    float* __restrict__ out)
{
    // [buf][kchunk(4)][row(128)][8 bf16] : 8 KB per buf per matrix, 32 KB total
    __shared__ __align__(16) unsigned short As[2 * 4096];
    __shared__ __align__(16) unsigned short Bs[2 * 4096];

    const int tid = threadIdx.x;
    const int e  = blockIdx.x & 7;          // expert == XCD (id%8 round-robin)
    const int g  = blockIdx.x >> 3;
    const int n0 = (g % NT) * 128;          // n fastest: reuse gathered A rows in L2
    const int m0 = (g / NT) * 128;

    // Staging: thread owns row r, 16B-chunks c0 and c0+2
    const int r  = tid & 127;
    const int c0 = tid >> 7;

    size_t arow_idx;
    if (!FUSE) {
        const int tok = stok[e * CAP + m0 + r];
        arow_idx = (size_t)(tok >= 0 ? tok : 0);   // dropped -> row 0 (weight 0 kills it)
    } else {
        arow_idx = (size_t)(e * CAP + m0 + r);
    }
    const unsigned short* arow = Abase + arow_idx * KD;
    const unsigned short* brow = Bt + ((size_t)e * ND + n0 + r) * KD;

    const int oA0 = (c0 * 128 + r) * 8;        // LDS elem offsets within a buf
    const int oA1 = ((c0 + 2) * 128 + r) * 8;

    const int lane = tid & 63;
    const int wid  = tid >> 6;
    const int wrow = (wid & 1) * 64;
    const int wcol = (wid >> 1) * 64;
    const int l15  = lane & 15;
    const int quad = lane >> 4;
    const int foff = quad * 128 + l15;

    f32x4 acc[4][4];
#pragma unroll
    for (int i = 0; i < 4; i++)
#pragma unroll
        for (int j = 0; j < 4; j++) acc[i][j] = (f32x4)0.f;

    // Prologue: tile 0 -> regs -> buf0; tile 1 -> regs
    float4 ra0 = *(const float4*)(arow + c0 * 8);
    float4 ra1 = *(const float4*)(arow + (c0 + 2) * 8);
    float4 rb0 = *(const float4*)(brow + c0 * 8);
    float4 rb1 = *(const float4*)(brow + (c0 + 2) * 8);
    *(float4*)(&As[oA0]) = ra0;
    *(float4*)(&As[oA1]) = ra1;
    *(float4*)(&Bs[oA0]) = rb0;
    *(float4*)(&Bs[oA1]) = rb1;
    if (32 < KD) {
        ra0 = *(const float4*)(arow + 32 + c0 * 8);
        ra1 = *(const float4*)(arow + 32 + (c0 + 2) * 8);
        rb0 = *(const float4*)(brow + 32 + c0 * 8);
        rb1 = *(const float4*)(brow + 32 + (c0 + 2) * 8);
    }
    __syncthreads();

#define COMPUTE(PBUF)                                                          \
    {                                                                          \
        const bf16x8* Av = (const bf16x8*)(As + (PBUF) * 4096);                \
        const bf16x8* Bv = (const bf16x8*)(Bs + (PBUF) * 4096);                \
        bf16x8 af[4], bfv[4];                                                  \
        _Pragma("unroll")                                                      \
        for (int i = 0; i < 4; i++) af[i]  = Av[foff + wrow + i * 16];         \
        _Pragma("unroll")                                                      \
        for (int j = 0; j < 4; j++) bfv[j] = Bv[foff + wcol + j * 16];         \
        _Pragma("unroll")                                                      \
        for (int i = 0; i < 4; i++)                                            \
            _Pragma("unroll")                                                  \
            for (int j = 0; j < 4; j++)                                        \
                acc[i][j] = __builtin_amdgcn_mfma_f32_16x16x32_bf16(           \
                    af[i], bfv[j], acc[i][j], 0, 0, 0);                        \
    }

    int rbuf = 0;
    for (int kc = 0; kc < KD; kc += 32) {
        const int wb = (rbuf ^ 1) * 4096;
        if (kc + 32 < KD) {
            // ds_write tile kc+32 (vmcnt wait: loads issued one iteration ago)
            *(float4*)(&As[wb + oA0]) = ra0;
            *(float4*)(&As[wb + oA1]) = ra1;
            *(float4*)(&Bs[wb + oA0]) = rb0;
            *(float4*)(&Bs[wb + oA1]) = rb1;
            if (kc + 64 < KD) {
                // issue tile kc+64 loads; in flight across compute + barrier
                ra0 = *(const float4*)(arow + kc + 64 + c0 * 8);
                ra1 = *(const float4*)(arow + kc + 64 + (c0 + 2) * 8);
                rb0 = *(const float4*)(brow + kc + 64 + c0 * 8);
                rb1 = *(const float4*)(brow + kc + 64 + (c0 + 2) * 8);
            }
        }
        COMPUTE(rbuf);
        __syncthreads();   // lgkm only — no vmcnt drain (no LDS-bound loads)
        rbuf ^= 1;
    }
#undef COMPUTE

    // Epilogue. C/D layout: col = lane&15, row = quad*4 + reg.
    if (!FUSE) {
#pragma unroll
        for (int i = 0; i < 4; i++) {
#pragma unroll
            for (int g2 = 0; g2 < 4; g2++) {
                const int m = wrow + i * 16 + quad * 4 + g2;
                unsigned short* hrow = hout + ((size_t)e * CAP + m0 + m) * FD + n0;
#pragma unroll
                for (int j = 0; j < 4; j++) {
                    const int n = wcol + j * 16 + l15;
                    const float v = acc[i][j][g2] + bias[(size_t)e * ND + n0 + n];
                    hrow[n] = f2bf(gelu_fast(v));
                }
            }
        }
    } else {
#pragma unroll
        for (int i = 0; i < 4; i++) {
#pragma unroll
            for (int g2 = 0; g2 < 4; g2++) {
                const int m = wrow + i * 16 + quad * 4 + g2;
                const int tok = stok[e * CAP + m0 + m];
                if (tok >= 0) {
                    const float w = swgt[e * CAP + m0 + m];
                    float* orow = out + (size_t)tok * HD + n0;
#pragma unroll
                    for (int j = 0; j < 4; j++) {
                        const int n = wcol + j * 16 + l15;
                        const float v = (acc[i][j][g2] + bias[(size_t)e * ND + n0 + n]) * w;
                        atomicAdd(orow + n, v);
                    }
                }
            }
        }
    }
}

extern "C" void kernel_launch(void* const* d_in, const int* in_sizes, int n_in,
                              void* d_out, int out_size, void* d_ws, size_t ws_size,
                              hipStream_t stream)
{
    const float* x  = (const float*)d_in[0];
    const float* rw = (const float*)d_in[1];
    const float* w1 = (const float*)d_in[2];
    const float* b1 = (const float*)d_in[3];
    const float* w2 = (const float*)d_in[4];
    const float* b2 = (const float*)d_in[5];
    float* out = (float*)d_out;

    char* ws = (char*)d_ws;
    int*   eidx = (int*)  (ws + OFF_EIDX);
    float* wgt  = (float*)(ws + OFF_WGT);
    int*   stok = (int*)  (ws + OFF_STOK);
    float* swgt = (float*)(ws + OFF_SWGT);
    unsigned short* w2t  = (unsigned short*)(ws + OFF_W2T);
    unsigned short* hbuf = (unsigned short*)(ws + OFF_H);
    unsigned short* w1t  = (unsigned short*)(ws + OFF_W1T);
    unsigned short* xbf  = (unsigned short*)(ws + OFF_XBF);

    transpose_cast_kernel<<<dim3(FD / 32, HD / 32, ED), 256, 0, stream>>>(w1, w1t, HD, FD);
    transpose_cast_kernel<<<dim3(HD / 32, FD / 32, ED), 256, 0, stream>>>(w2, w2t, FD, HD);
    router_kernel<<<NTOK / 4, 256, 0, stream>>>(x, rw, eidx, wgt, xbf);
    scan_kernel<<<1, 1024, 0, stream>>>(eidx, wgt, stok, swgt);
    hipMemsetAsync(d_out, 0, (size_t)out_size * sizeof(float), stream);

    // GEMM1: h = gelu(gather(x) @ w1 + b1)  [bf16]
    gemm_mfma<HD, FD, FD/128, false>
        <<<8 * (FD/128) * (CAP/128), 256, 0, stream>>>(
        xbf, w1t, b1, stok, nullptr, hbuf, nullptr);

    // GEMM2 + fused combine: out[tok] += (h @ w2 + b2) * weight
    gemm_mfma<FD, HD, HD/128, true>
        <<<8 * (HD/128) * (CAP/128), 256, 0, stream>>>(
        hbuf, w2t, b2, stok, swgt, nullptr, out);
}

// Round 8
// 521.497 us; speedup vs baseline: 1.6773x; 1.2061x over previous
//
#include <hip/hip_runtime.h>
#include <hip/hip_bf16.h>

// Problem constants (static per reference)
#define NTOK 16384   // B*T
#define HD   512     // H
#define ED   8       // E experts
#define FD   2048    // F
#define CAP  5120    // capacity per expert
#define NA   32768   // NTOK * K(=2)

typedef __bf16 bf16x8 __attribute__((ext_vector_type(8)));
typedef float  f32x4  __attribute__((ext_vector_type(4)));

// Workspace layout (bytes). Total ~218 MB.
static constexpr size_t OFF_EIDX = 0;                                  // int[NA]
static constexpr size_t OFF_WGT  = 131072;                             // float[NA]
static constexpr size_t OFF_STOK = 262144;                             // int[ED*CAP]
static constexpr size_t OFF_SWGT = 458752;                             // float[ED*CAP]
static constexpr size_t OFF_W2T  = 1u << 20;                           // bf16[ED][HD][FD]
static constexpr size_t OFF_H    = OFF_W2T + (size_t)ED*HD*FD*2;       // bf16[ED][CAP][FD]
static constexpr size_t OFF_W1T  = OFF_H   + (size_t)ED*CAP*FD*2;      // bf16[ED][FD][HD]
static constexpr size_t OFF_XBF  = OFF_W1T + (size_t)ED*FD*HD*2;       // bf16[NTOK][HD]

__device__ __forceinline__ unsigned short f2bf(float f) {
    __bf16 b = (__bf16)f;
    return __builtin_bit_cast(unsigned short, b);
}

// gelu(tanh approx) == v * sigmoid(2*0.79788456*(v + 0.044715 v^3))  (exact identity)
__device__ __forceinline__ float gelu_fast(float v) {
    const float u = 1.5957691216057308f * (v + 0.044715f * v * v * v);
    return v / (1.f + __expf(-u));
}

// ---------------------------------------------------------------------------
// in: [R][C] fp32 (per expert)  ->  out: [C][R] bf16 (per expert)
// ---------------------------------------------------------------------------
__global__ __launch_bounds__(256) void transpose_cast_kernel(
    const float* __restrict__ in, unsigned short* __restrict__ out, int R, int C)
{
    __shared__ unsigned short tile[32][33];
    const int e = blockIdx.z;
    in  += (size_t)e * R * C;
    out += (size_t)e * R * C;
    const int r0 = blockIdx.y * 32, c0 = blockIdx.x * 32;
    const int tr = threadIdx.x >> 3, tc = (threadIdx.x & 7) * 4;
    const float4 v = *(const float4*)(in + (size_t)(r0 + tr) * C + c0 + tc);
    tile[tr][tc + 0] = f2bf(v.x);
    tile[tr][tc + 1] = f2bf(v.y);
    tile[tr][tc + 2] = f2bf(v.z);
    tile[tr][tc + 3] = f2bf(v.w);
    __syncthreads();
    ushort4 o;
    o.x = tile[tc + 0][tr]; o.y = tile[tc + 1][tr];
    o.z = tile[tc + 2][tr]; o.w = tile[tc + 3][tr];
    *(ushort4*)(out + (size_t)(c0 + tr) * R + r0 + tc) = o;
}

// ---------------------------------------------------------------------------
// Router (+ fused x->bf16 cast): logits = x @ router_w (fp32), top-2, softmax.
// ---------------------------------------------------------------------------
__global__ __launch_bounds__(256) void router_kernel(
    const float* __restrict__ x, const float* __restrict__ rw,
    int* __restrict__ eidx, float* __restrict__ wgt,
    unsigned short* __restrict__ xbf)
{
    __shared__ float rws[HD * ED];
    const int tid = threadIdx.x;
    for (int i = tid * 4; i < HD * ED; i += 256 * 4)
        *(float4*)(rws + i) = *(const float4*)(rw + i);
    __syncthreads();

    const int wid = tid >> 6, lane = tid & 63;
    const int t = blockIdx.x * 4 + wid;
    const float* xr = x + (size_t)t * HD;

    float acc[ED];
#pragma unroll
    for (int e = 0; e < ED; e++) acc[e] = 0.f;

    float4 xv0 = *(const float4*)(xr + lane * 8);
    float4 xv1 = *(const float4*)(xr + lane * 8 + 4);
    float xv[8] = {xv0.x, xv0.y, xv0.z, xv0.w, xv1.x, xv1.y, xv1.z, xv1.w};

    union { unsigned short us[8]; uint4 v; } pk;
#pragma unroll
    for (int j = 0; j < 8; j++) pk.us[j] = f2bf(xv[j]);
    *(uint4*)(xbf + (size_t)t * HD + lane * 8) = pk.v;

#pragma unroll
    for (int j = 0; j < 8; j++) {
        const int h = lane * 8 + j;
#pragma unroll
        for (int e = 0; e < ED; e++) acc[e] += xv[j] * rws[h * ED + e];
    }
#pragma unroll
    for (int off = 32; off >= 1; off >>= 1) {
#pragma unroll
        for (int e = 0; e < ED; e++) acc[e] += __shfl_down(acc[e], off);
    }
    if (lane == 0) {
        int e0 = 0; float l0 = acc[0];
        for (int e = 1; e < ED; e++) if (acc[e] > l0) { l0 = acc[e]; e0 = e; }
        int e1 = 0; float l1 = -1e30f;
        for (int e = 0; e < ED; e++) {
            if (e == e0) continue;
            if (acc[e] > l1) { l1 = acc[e]; e1 = e; }
        }
        const float ex = expf(l1 - l0);
        const float inv = 1.f / (1.f + ex);
        eidx[t * 2 + 0] = e0;  eidx[t * 2 + 1] = e1;
        wgt [t * 2 + 0] = inv; wgt [t * 2 + 1] = ex * inv;
    }
}

// ---------------------------------------------------------------------------
// Deterministic slot assignment (stable-sort-by-expert semantics).
// ---------------------------------------------------------------------------
__global__ __launch_bounds__(1024) void scan_kernel(
    const int* __restrict__ eidx, const float* __restrict__ wgt,
    int* __restrict__ stok, float* __restrict__ swgt)
{
    __shared__ int running[ED];
    __shared__ int wcnt[16][ED];
    const int tid = threadIdx.x;

    for (int i = tid; i < ED * CAP; i += 1024) stok[i] = -1;
    if (tid < ED) running[tid] = 0;
    __syncthreads();

    const int lane = tid & 63, wid = tid >> 6;
    const unsigned long long below = (1ull << lane) - 1ull;

    for (int c = 0; c < NA / 1024; c++) {
        const int a = c * 1024 + tid;
        const int e = eidx[a];
        const float w = wgt[a];
        int myrank = 0;
#pragma unroll
        for (int ee = 0; ee < ED; ee++) {
            unsigned long long m = __ballot(e == ee);
            if (ee == e) myrank = __popcll(m & below);
            if (lane == 0) wcnt[wid][ee] = __popcll(m);
        }
        __syncthreads();
        int woff = 0;
        for (int ww = 0; ww < wid; ww++) woff += wcnt[ww][e];
        const int slot = running[e] + woff + myrank;
        if (slot < CAP) {
            stok[e * CAP + slot] = a >> 1;   // token = a / K
            swgt[e * CAP + slot] = w;
        }
        __syncthreads();
        if (tid < ED) {
            int tot = 0;
            for (int ww = 0; ww < 16; ww++) tot += wcnt[ww][tid];
            running[tid] += tot;
        }
        __syncthreads();
    }
}

// ---------------------------------------------------------------------------
// MFMA GEMM, VGPR-staged pipeline with COALESCED staging (the R8 change):
// BK=32 subtile is loaded row-major — lanes 0..3 read one row's 64 B, so a
// wave-instruction touches 16 cache lines instead of 64 (4x fewer VMEM
// transactions; this was the binding constraint in R2..R7).
// LDS layout [row(128)][40] (32 k-elems + 8 pad): 80 B row stride keeps
// ds_read_b128 16B-aligned and bank starts stride-20 (<=2-way, free).
// Pipeline: ONE barrier per K-step; loads issued one iteration ahead of
// their ds_write so the vmcnt wait is a full compute phase after issue.
// Mapping: id%8 == expert == XCD; n fastest so gathered A rows are fetched
// into L2 once and reused by all n-tiles; expert weight slab L2-resident.
// FUSE=false: hout = gelu(A@B + bias) [bf16]. FUSE=true: atomic combine.
// ---------------------------------------------------------------------------
template<int KD, int ND, int NT, bool FUSE>
__global__ __launch_bounds__(256) void gemm_mfma(
    const unsigned short* __restrict__ Abase,
    const unsigned short* __restrict__ Bt,
    const float* __restrict__ bias,
    const int* __restrict__ stok,
    const float* __restrict__ swgt,
    unsigned short* __restrict__ hout,
    float* __restrict__ out)
{
    // [buf][row(128)][40 elems]: 10240 B per matrix per buf, 40 KB total
    constexpr int RS   = 40;          // row stride (elements)
    constexpr int BUFE = 128 * RS;    // 5120 elements per buf
    __shared__ __align__(16) unsigned short As[2 * BUFE];
    __shared__ __align__(16) unsigned short Bs[2 * BUFE];

    const int tid = threadIdx.x;
    const int e  = blockIdx.x & 7;          // expert == XCD (id%8 round-robin)
    const int g  = blockIdx.x >> 3;
    const int n0 = (g % NT) * 128;          // n fastest: reuse gathered A rows in L2
    const int m0 = (g / NT) * 128;

    // Coalesced staging: thread covers rows r1, r1+64; 16B chunk q within BK=32
    const int q  = tid & 3;
    const int r1 = tid >> 2;                // 0..63
    const int r2 = r1 + 64;

    size_t ai1, ai2;
    if (!FUSE) {
        const int t1 = stok[e * CAP + m0 + r1];
        const int t2 = stok[e * CAP + m0 + r2];
        ai1 = (size_t)(t1 >= 0 ? t1 : 0);   // dropped -> row 0 (weight 0 kills it)
        ai2 = (size_t)(t2 >= 0 ? t2 : 0);
    } else {
        ai1 = (size_t)(e * CAP + m0 + r1);
        ai2 = (size_t)(e * CAP + m0 + r2);
    }
    const unsigned short* arow1 = Abase + ai1 * KD + q * 8;
    const unsigned short* arow2 = Abase + ai2 * KD + q * 8;
    const unsigned short* brow1 = Bt + ((size_t)e * ND + n0 + r1) * KD + q * 8;
    const unsigned short* brow2 = Bt + ((size_t)e * ND + n0 + r2) * KD + q * 8;

    const int oW1 = r1 * RS + q * 8;        // ds_write elem offsets within a buf
    const int oW2 = r2 * RS + q * 8;

    const int lane = tid & 63;
    const int wid  = tid >> 6;
    const int wrow = (wid & 1) * 64;
    const int wcol = (wid >> 1) * 64;
    const int l15  = lane & 15;
    const int quad = lane >> 4;
    const int fA   = (wrow + l15) * RS + quad * 8;  // fragment read bases
    const int fB   = (wcol + l15) * RS + quad * 8;

    f32x4 acc[4][4];
#pragma unroll
    for (int i = 0; i < 4; i++)
#pragma unroll
        for (int j = 0; j < 4; j++) acc[i][j] = (f32x4)0.f;

    // Prologue: tile 0 -> regs -> buf0; tile 1 -> regs
    float4 ra1 = *(const float4*)(arow1);
    float4 ra2 = *(const float4*)(arow2);
    float4 rb1 = *(const float4*)(brow1);
    float4 rb2 = *(const float4*)(brow2);
    *(float4*)(&As[oW1]) = ra1;
    *(float4*)(&As[oW2]) = ra2;
    *(float4*)(&Bs[oW1]) = rb1;
    *(float4*)(&Bs[oW2]) = rb2;
    if (32 < KD) {
        ra1 = *(const float4*)(arow1 + 32);
        ra2 = *(const float4*)(arow2 + 32);
        rb1 = *(const float4*)(brow1 + 32);
        rb2 = *(const float4*)(brow2 + 32);
    }
    __syncthreads();

#define COMPUTE(PBUF)                                                          \
    {                                                                          \
        const unsigned short* Ab = As + (PBUF) * BUFE;                         \
        const unsigned short* Bb = Bs + (PBUF) * BUFE;                         \
        bf16x8 af[4], bfv[4];                                                  \
        _Pragma("unroll")                                                      \
        for (int i = 0; i < 4; i++) af[i]  = *(const bf16x8*)(Ab + fA + i * 16 * RS); \
        _Pragma("unroll")                                                      \
        for (int j = 0; j < 4; j++) bfv[j] = *(const bf16x8*)(Bb + fB + j * 16 * RS); \
        _Pragma("unroll")                                                      \
        for (int i = 0; i < 4; i++)                                            \
            _Pragma("unroll")                                                  \
            for (int j = 0; j < 4; j++)                                        \
                acc[i][j] = __builtin_amdgcn_mfma_f32_16x16x32_bf16(           \
                    af[i], bfv[j], acc[i][j], 0, 0, 0);                        \
    }

    int rbuf = 0;
    for (int kc = 0; kc < KD; kc += 32) {
        const int wb = (rbuf ^ 1) * BUFE;
        if (kc + 32 < KD) {
            // ds_write tile kc+32 (vmcnt wait: loads issued one iteration ago)
            *(float4*)(&As[wb + oW1]) = ra1;
            *(float4*)(&As[wb + oW2]) = ra2;
            *(float4*)(&Bs[wb + oW1]) = rb1;
            *(float4*)(&Bs[wb + oW2]) = rb2;
            if (kc + 64 < KD) {
                ra1 = *(const float4*)(arow1 + kc + 64);
                ra2 = *(const float4*)(arow2 + kc + 64);
                rb1 = *(const float4*)(brow1 + kc + 64);
                rb2 = *(const float4*)(brow2 + kc + 64);
            }
        }
        COMPUTE(rbuf);
        __syncthreads();   // lgkm only — no vmcnt drain (no LDS-bound loads)
        rbuf ^= 1;
    }
#undef COMPUTE

    // Epilogue. C/D layout: col = lane&15, row = quad*4 + reg.
    if (!FUSE) {
#pragma unroll
        for (int i = 0; i < 4; i++) {
#pragma unroll
            for (int g2 = 0; g2 < 4; g2++) {
                const int m = wrow + i * 16 + quad * 4 + g2;
                unsigned short* hrow = hout + ((size_t)e * CAP + m0 + m) * FD + n0;
#pragma unroll
                for (int j = 0; j < 4; j++) {
                    const int n = wcol + j * 16 + l15;
                    const float v = acc[i][j][g2] + bias[(size_t)e * ND + n0 + n];
                    hrow[n] = f2bf(gelu_fast(v));
                }
            }
        }
    } else {
#pragma unroll
        for (int i = 0; i < 4; i++) {
#pragma unroll
            for (int g2 = 0; g2 < 4; g2++) {
                const int m = wrow + i * 16 + quad * 4 + g2;
                const int tok = stok[e * CAP + m0 + m];
                if (tok >= 0) {
                    const float w = swgt[e * CAP + m0 + m];
                    float* orow = out + (size_t)tok * HD + n0;
#pragma unroll
                    for (int j = 0; j < 4; j++) {
                        const int n = wcol + j * 16 + l15;
                        const float v = (acc[i][j][g2] + bias[(size_t)e * ND + n0 + n]) * w;
                        atomicAdd(orow + n, v);
                    }
                }
            }
        }
    }
}

extern "C" void kernel_launch(void* const* d_in, const int* in_sizes, int n_in,
                              void* d_out, int out_size, void* d_ws, size_t ws_size,
                              hipStream_t stream)
{
    const float* x  = (const float*)d_in[0];
    const float* rw = (const float*)d_in[1];
    const float* w1 = (const float*)d_in[2];
    const float* b1 = (const float*)d_in[3];
    const float* w2 = (const float*)d_in[4];
    const float* b2 = (const float*)d_in[5];
    float* out = (float*)d_out;

    char* ws = (char*)d_ws;
    int*   eidx = (int*)  (ws + OFF_EIDX);
    float* wgt  = (float*)(ws + OFF_WGT);
    int*   stok = (int*)  (ws + OFF_STOK);
    float* swgt = (float*)(ws + OFF_SWGT);
    unsigned short* w2t  = (unsigned short*)(ws + OFF_W2T);
    unsigned short* hbuf = (unsigned short*)(ws + OFF_H);
    unsigned short* w1t  = (unsigned short*)(ws + OFF_W1T);
    unsigned short* xbf  = (unsigned short*)(ws + OFF_XBF);

    transpose_cast_kernel<<<dim3(FD / 32, HD / 32, ED), 256, 0, stream>>>(w1, w1t, HD, FD);
    transpose_cast_kernel<<<dim3(HD / 32, FD / 32, ED), 256, 0, stream>>>(w2, w2t, FD, HD);
    router_kernel<<<NTOK / 4, 256, 0, stream>>>(x, rw, eidx, wgt, xbf);
    scan_kernel<<<1, 1024, 0, stream>>>(eidx, wgt, stok, swgt);
    hipMemsetAsync(d_out, 0, (size_t)out_size * sizeof(float), stream);

    // GEMM1: h = gelu(gather(x) @ w1 + b1)  [bf16]
    gemm_mfma<HD, FD, FD/128, false>
        <<<8 * (FD/128) * (CAP/128), 256, 0, stream>>>(
        xbf, w1t, b1, stok, nullptr, hbuf, nullptr);

    // GEMM2 + fused combine: out[tok] += (h @ w2 + b2) * weight
    gemm_mfma<FD, HD, HD/128, true>
        <<<8 * (HD/128) * (CAP/128), 256, 0, stream>>>(
        hbuf, w2t, b2, stok, swgt, nullptr, out);
}